// Round 13
// baseline (285.794 us; speedup 1.0000x reference)
//
#include <hip/hip_runtime.h>
#include <hip/hip_fp16.h>

#define NN 50000
#define NE 800000
#define NBKT 782          // ceil(NN/64) coarse buckets of 64 dests
#define CB 128            // scatter blocks
#define ECAP 1280         // fixed temp capacity per bucket (mean 1024, +8 sigma)
#define SCAP 1344         // sedge capacity per bucket (ECAP + 64 self slots)
#define EPSB 1e-5f
#define SLOPE 0.01f

// workspace layout (4-byte element offsets)
#define W_SEDGE 0          // NBKT*SCAP u32 = 1,051,008
#define W_OFFS  1051008    // NN ints
#define W_OFFE  1101008    // NN ints
#define W_DIS   1151008    // NN floats
#define W_CNTG  1201008    // NBKT ints (zeroed)
#define W_SUM1  1201792    // 128 (zeroed)
#define W_SQ1   1201920    // 128
#define W_SUM2  1202048    // 64
#define W_SQ2   1202112    // 64
#define W_TEMP  1202176    // NBKT*ECAP int2 = 2,001,920 ints (8B aligned: even)
#define W_H1    3204096    // N*128 fp16 = 3.2M float slots (H2 aliases)
#define W_O1    6404096    // N*128 fp16 = 3.2M float slots

union H8 { uint4 u; __half2 h[4]; };
typedef _Float16 f16x8 __attribute__((ext_vector_type(8)));
typedef float f32x4 __attribute__((ext_vector_type(4)));

// scatter with self-reserved bucket ranges (unchanged from R11)
__global__ __launch_bounds__(256) void k_scatC2(const int* __restrict__ adj,
                                                const float* __restrict__ w,
                                                int* __restrict__ cnt_g,
                                                int2* __restrict__ temp) {
  __shared__ int h[NBKT];
  __shared__ int cur[NBKT];
  for (int i = threadIdx.x; i < NBKT; i += 256) h[i] = 0;
  __syncthreads();
  const int per = (NE + CB - 1) / CB;
  int lo = blockIdx.x * per, hi = min(lo + per, NE);
  for (int e = lo + threadIdx.x; e < hi; e += 256)
    atomicAdd(&h[adj[NE + e] >> 6], 1);
  __syncthreads();
  for (int i = threadIdx.x; i < NBKT; i += 256) {
    int c = h[i];
    int base = c ? atomicAdd(&cnt_g[i], c) : 0;
    cur[i] = i * ECAP + base;
  }
  __syncthreads();
  for (int e = lo + threadIdx.x; e < hi; e += 256) {
    int r = adj[e], c = adj[NE + e];
    int b = c >> 6;
    int slot = atomicAdd(&cur[b], 1);
    if (slot < (b + 1) * ECAP)
      temp[slot] = make_int2((r << 6) | (c & 63), __float_as_int(w[e]));
  }
}

// per-bucket binning (unchanged from R11)
__global__ __launch_bounds__(256) void k_binD2(const int2* __restrict__ temp,
                                               const int* __restrict__ cnt_g,
                                               float* __restrict__ dis,
                                               int* __restrict__ offS,
                                               int* __restrict__ offE,
                                               unsigned* __restrict__ sedge) {
  int k = blockIdx.x;
  int Tk = min(cnt_g[k], ECAP);
  int d0 = k << 6;
  int nd = min(64, NN - d0);
  int fbase = k * SCAP;
  const int2* tb = temp + (size_t)k * ECAP;
  __shared__ int cnt[64];
  __shared__ float wsum[64];
  __shared__ int lpos[64];
  __shared__ unsigned ob[SCAP];
  if (threadIdx.x < 64) { cnt[threadIdx.x] = 0; wsum[threadIdx.x] = 0.f; }
  __syncthreads();
  for (int i = threadIdx.x; i < Tk; i += 256) {
    int2 e = tb[i];
    int dl = e.x & 63;
    atomicAdd(&cnt[dl], 1);
    atomicAdd(&wsum[dl], __int_as_float(e.y));
  }
  __syncthreads();
  if (threadIdx.x < 64) {
    int lane = threadIdx.x;
    int c = (lane < nd) ? cnt[lane] + 1 : 0;
    int v = c;
#pragma unroll
    for (int o = 1; o < 64; o <<= 1) {
      int u = __shfl_up(v, o, 64);
      if (lane >= o) v += u;
    }
    int base = v - c;
    if (lane < nd) {
      dis[d0 + lane] = rsqrtf(wsum[lane] + 1.0f);
      offS[d0 + lane] = fbase + base;
      offE[d0 + lane] = fbase + base + c;
      ob[base] = ((unsigned)(d0 + lane) << 16) | 0x3C00u;  // self: fp16(1.0)
      lpos[lane] = base + 1;
    }
  }
  __syncthreads();
  for (int i = threadIdx.x; i < Tk; i += 256) {
    int2 e = tb[i];
    int dl = e.x & 63;
    unsigned src = ((unsigned)e.x) >> 6;
    int slot = atomicAdd(&lpos[dl], 1);
    __half hw = __float2half(__int_as_float(e.y));
    ob[slot] = (src << 16) | (unsigned)__half_as_ushort(hw);
  }
  __syncthreads();
  int tot = Tk + nd;
  for (int i = threadIdx.x; i < tot; i += 256)
    sedge[fbase + i] = ob[i];
}

// ---------------- MFMA GEMM1: H1'(fp16) = dis[r] * (X @ W1) ----------------
__global__ __launch_bounds__(256) void k_gemm1m(const float* __restrict__ X,
                                                const float* __restrict__ W1,
                                                const float* __restrict__ dis,
                                                __half* __restrict__ H) {
  __shared__ _Float16 xs[64 * 128];
  __shared__ _Float16 wt[128 * 128];
  char* xsb = (char*)xs;
  char* wtb = (char*)wt;
  int tid = threadIdx.x;
  int row0 = blockIdx.x * 64;
  for (int i = tid; i < 64 * 32; i += 256) {
    int r = i >> 5, c4 = i & 31;
    float4 v = (row0 + r < NN) ? ((const float4*)X)[(size_t)(row0 + r) * 32 + c4]
                               : make_float4(0.f, 0.f, 0.f, 0.f);
    union { _Float16 h[4]; uint2 u; } p;
    p.h[0] = (_Float16)v.x; p.h[1] = (_Float16)v.y;
    p.h[2] = (_Float16)v.z; p.h[3] = (_Float16)v.w;
    int byte = (r * 256 + c4 * 8) ^ ((r & 7) << 4);
    *(uint2*)(xsb + byte) = p.u;
  }
  for (int i = tid; i < 128 * 32; i += 256) {
    int k = i >> 5, n4 = i & 31;
    float4 v = ((const float4*)W1)[k * 32 + n4];
    float vv[4] = {v.x, v.y, v.z, v.w};
#pragma unroll
    for (int j = 0; j < 4; ++j) {
      int n = n4 * 4 + j;
      int byte = (n * 256 + k * 2) ^ ((n & 7) << 4);
      *(_Float16*)(wtb + byte) = (_Float16)vv[j];
    }
  }
  __syncthreads();
  int l = tid & 63, w = tid >> 6;
  int lr = l & 15, lk2 = ((l >> 4) << 3) * 2;
  f32x4 acc[8];
#pragma unroll
  for (int nt = 0; nt < 8; ++nt) acc[nt] = (f32x4){0.f, 0.f, 0.f, 0.f};
  int arow = w * 16 + lr;
  int asw = (arow & 7) << 4;
  int nsw = (lr & 7) << 4;
#pragma unroll
  for (int ks = 0; ks < 4; ++ks) {
    int kb = ks * 64 + lk2;
    f16x8 a = *(const f16x8*)(xsb + arow * 256 + (kb ^ asw));
#pragma unroll
    for (int nt = 0; nt < 8; ++nt) {
      int n = nt * 16 + lr;
      f16x8 b = *(const f16x8*)(wtb + n * 256 + (kb ^ nsw));
      acc[nt] = __builtin_amdgcn_mfma_f32_16x16x32_f16(a, b, acc[nt], 0, 0, 0);
    }
  }
  int orow = row0 + w * 16 + ((l >> 4) << 2);
#pragma unroll
  for (int r = 0; r < 4; ++r) {
    if (orow + r < NN) {
      float ds = dis[orow + r];
      __half* Hp = &H[(size_t)(orow + r) * 128 + lr];
#pragma unroll
      for (int nt = 0; nt < 8; ++nt)
        Hp[nt * 16] = __float2half(acc[nt][r] * ds);
    }
  }
}

// pull-gather layer1: O(fp16)[c,:] = b1 + dis[c] * sum w * H'[src,:]
// 32 lanes x uint2 per node, 8 nodes per 256-block, unroll x4
__global__ __launch_bounds__(256) void k_gather1(const int* __restrict__ offS,
                                                 const int* __restrict__ offE,
                                                 const unsigned* __restrict__ sedge,
                                                 const float* __restrict__ dis,
                                                 const __half* __restrict__ H,
                                                 const float* __restrict__ b1,
                                                 __half* __restrict__ O) {
  int node = blockIdx.x * 8 + (threadIdx.x >> 5);
  int f4 = threadIdx.x & 31;
  const uint2* Hh = (const uint2*)H;
  float4 acc = make_float4(0.f, 0.f, 0.f, 0.f);
  float dc = dis[node];
  int j0 = offS[node], j1 = offE[node];
  int j = j0;
  for (; j + 3 < j1; j += 4) {
    unsigned u0 = sedge[j], u1 = sedge[j + 1];
    unsigned u2 = sedge[j + 2], u3 = sedge[j + 3];
    uint2 r0 = Hh[(size_t)(u0 >> 16) * 32 + f4];
    uint2 r1 = Hh[(size_t)(u1 >> 16) * 32 + f4];
    uint2 r2 = Hh[(size_t)(u2 >> 16) * 32 + f4];
    uint2 r3 = Hh[(size_t)(u3 >> 16) * 32 + f4];
    float n0 = __half2float(__ushort_as_half((unsigned short)(u0 & 0xFFFFu)));
    float n1 = __half2float(__ushort_as_half((unsigned short)(u1 & 0xFFFFu)));
    float n2 = __half2float(__ushort_as_half((unsigned short)(u2 & 0xFFFFu)));
    float n3 = __half2float(__ushort_as_half((unsigned short)(u3 & 0xFFFFu)));
    float2 a0 = __half22float2(*(__half2*)&r0.x);
    float2 c0 = __half22float2(*(__half2*)&r0.y);
    float2 a1 = __half22float2(*(__half2*)&r1.x);
    float2 c1 = __half22float2(*(__half2*)&r1.y);
    float2 a2 = __half22float2(*(__half2*)&r2.x);
    float2 c2 = __half22float2(*(__half2*)&r2.y);
    float2 a3 = __half22float2(*(__half2*)&r3.x);
    float2 c3 = __half22float2(*(__half2*)&r3.y);
    acc.x = fmaf(a0.x, n0, acc.x); acc.y = fmaf(a0.y, n0, acc.y);
    acc.z = fmaf(c0.x, n0, acc.z); acc.w = fmaf(c0.y, n0, acc.w);
    acc.x = fmaf(a1.x, n1, acc.x); acc.y = fmaf(a1.y, n1, acc.y);
    acc.z = fmaf(c1.x, n1, acc.z); acc.w = fmaf(c1.y, n1, acc.w);
    acc.x = fmaf(a2.x, n2, acc.x); acc.y = fmaf(a2.y, n2, acc.y);
    acc.z = fmaf(c2.x, n2, acc.z); acc.w = fmaf(c2.y, n2, acc.w);
    acc.x = fmaf(a3.x, n3, acc.x); acc.y = fmaf(a3.y, n3, acc.y);
    acc.z = fmaf(c3.x, n3, acc.z); acc.w = fmaf(c3.y, n3, acc.w);
  }
  for (; j < j1; ++j) {
    unsigned u = sedge[j];
    uint2 r = Hh[(size_t)(u >> 16) * 32 + f4];
    float nm = __half2float(__ushort_as_half((unsigned short)(u & 0xFFFFu)));
    float2 a = __half22float2(*(__half2*)&r.x);
    float2 b = __half22float2(*(__half2*)&r.y);
    acc.x = fmaf(a.x, nm, acc.x); acc.y = fmaf(a.y, nm, acc.y);
    acc.z = fmaf(b.x, nm, acc.z); acc.w = fmaf(b.y, nm, acc.w);
  }
  float4 bl = ((const float4*)b1)[f4];
  float o0 = fmaf(acc.x, dc, bl.x);
  float o1 = fmaf(acc.y, dc, bl.y);
  float o2 = fmaf(acc.z, dc, bl.z);
  float o3 = fmaf(acc.w, dc, bl.w);
  uint2 o;
  *(__half2*)&o.x = __floats2half2_rn(o0, o1);
  *(__half2*)&o.y = __floats2half2_rn(o2, o3);
  ((uint2*)O)[(size_t)node * 32 + f4] = o;
}

__global__ __launch_bounds__(256) void k_statsh(const __half* __restrict__ X,
                                                float* __restrict__ sum,
                                                float* __restrict__ sq) {
  int f2 = threadIdx.x & 63;
  int rg = threadIdx.x >> 6;
  float sx = 0.f, sy = 0.f, ssx = 0.f, ssy = 0.f;
  const unsigned* X2 = (const unsigned*)X;
  for (int r = blockIdx.x * 4 + rg; r < NN; r += gridDim.x * 4) {
    unsigned u = X2[(size_t)r * 64 + f2];
    float2 v = __half22float2(*(__half2*)&u);
    sx += v.x; sy += v.y;
    ssx += v.x * v.x; ssy += v.y * v.y;
  }
  __shared__ float ls[256][4];
  ls[threadIdx.x][0] = sx; ls[threadIdx.x][1] = sy;
  ls[threadIdx.x][2] = ssx; ls[threadIdx.x][3] = ssy;
  __syncthreads();
  if (rg == 0) {
    for (int g = 1; g < 4; ++g) {
      sx += ls[g * 64 + f2][0]; sy += ls[g * 64 + f2][1];
      ssx += ls[g * 64 + f2][2]; ssy += ls[g * 64 + f2][3];
    }
    atomicAdd(&sum[2 * f2], sx);
    atomicAdd(&sum[2 * f2 + 1], sy);
    atomicAdd(&sq[2 * f2], ssx);
    atomicAdd(&sq[2 * f2 + 1], ssy);
  }
}

__global__ void k_stats(const float* __restrict__ X, float* __restrict__ sum,
                        float* __restrict__ sq, int C) {
  int f = threadIdx.x & (C - 1);
  int rg = threadIdx.x / C;
  int nrg = 256 / C;
  float s = 0.f, ss = 0.f;
  for (int r = blockIdx.x * nrg + rg; r < NN; r += gridDim.x * nrg) {
    float v = X[(size_t)r * C + f];
    s += v;
    ss += v * v;
  }
  __shared__ float ls[256], lss[256];
  ls[threadIdx.x] = s;
  lss[threadIdx.x] = ss;
  __syncthreads();
  if (rg == 0) {
    for (int g = 1; g < nrg; ++g) { s += ls[g * C + f]; ss += lss[g * C + f]; }
    atomicAdd(&sum[f], s);
    atomicAdd(&sq[f], ss);
  }
}

// ---------------- MFMA GEMM2: H2'(fp16) = dis[r] * (leaky(BN1(O1)) @ W2) ----
__global__ __launch_bounds__(256) void k_gemm2m(const __half* __restrict__ O1,
                                                const float* __restrict__ W2,
                                                const float* __restrict__ sum1,
                                                const float* __restrict__ sq1,
                                                const float* __restrict__ g1,
                                                const float* __restrict__ be1,
                                                const float* __restrict__ dis,
                                                __half* __restrict__ H2) {
  __shared__ _Float16 xs[64 * 128];
  __shared__ _Float16 wt[64 * 128];
  __shared__ float a1s[128], c1s[128];
  char* xsb = (char*)xs;
  char* wtb = (char*)wt;
  int tid = threadIdx.x;
  if (tid < 128) {
    float mu = sum1[tid] * (1.0f / NN);
    float var = sq1[tid] * (1.0f / NN) - mu * mu;
    float a = g1[tid] * rsqrtf(var + EPSB);
    a1s[tid] = a;
    c1s[tid] = be1[tid] - mu * a;
  }
  __syncthreads();
  int row0 = blockIdx.x * 64;
  for (int i = tid; i < 64 * 16; i += 256) {
    int r = i >> 4, k8 = i & 15;
    H8 t;
    t.u = (row0 + r < NN) ? ((const uint4*)O1)[(size_t)(row0 + r) * 16 + k8]
                          : make_uint4(0, 0, 0, 0);
    union { _Float16 h[8]; uint4 u; } p;
#pragma unroll
    for (int jj = 0; jj < 4; ++jj) {
      float2 v = __half22float2(t.h[jj]);
      int fb = k8 * 8 + jj * 2;
      float y0 = fmaf(a1s[fb], v.x, c1s[fb]);
      float y1 = fmaf(a1s[fb + 1], v.y, c1s[fb + 1]);
      y0 = y0 >= 0.f ? y0 : SLOPE * y0;
      y1 = y1 >= 0.f ? y1 : SLOPE * y1;
      p.h[jj * 2] = (_Float16)y0;
      p.h[jj * 2 + 1] = (_Float16)y1;
    }
    int byte = (r * 256 + k8 * 16) ^ ((r & 7) << 4);
    *(uint4*)(xsb + byte) = p.u;
  }
  for (int i = tid; i < 128 * 16; i += 256) {
    int k = i >> 4, n4 = i & 15;
    float4 v = ((const float4*)W2)[k * 16 + n4];
    float vv[4] = {v.x, v.y, v.z, v.w};
#pragma unroll
    for (int j = 0; j < 4; ++j) {
      int n = n4 * 4 + j;
      int byte = (n * 256 + k * 2) ^ ((n & 7) << 4);
      *(_Float16*)(wtb + byte) = (_Float16)vv[j];
    }
  }
  __syncthreads();
  int l = tid & 63, w = tid >> 6;
  int lr = l & 15, lk2 = ((l >> 4) << 3) * 2;
  f32x4 acc[4];
#pragma unroll
  for (int nt = 0; nt < 4; ++nt) acc[nt] = (f32x4){0.f, 0.f, 0.f, 0.f};
  int arow = w * 16 + lr;
  int asw = (arow & 7) << 4;
  int nsw = (lr & 7) << 4;
#pragma unroll
  for (int ks = 0; ks < 4; ++ks) {
    int kb = ks * 64 + lk2;
    f16x8 a = *(const f16x8*)(xsb + arow * 256 + (kb ^ asw));
#pragma unroll
    for (int nt = 0; nt < 4; ++nt) {
      int n = nt * 16 + lr;
      f16x8 b = *(const f16x8*)(wtb + n * 256 + (kb ^ nsw));
      acc[nt] = __builtin_amdgcn_mfma_f32_16x16x32_f16(a, b, acc[nt], 0, 0, 0);
    }
  }
  int orow = row0 + w * 16 + ((l >> 4) << 2);
#pragma unroll
  for (int r = 0; r < 4; ++r) {
    if (orow + r < NN) {
      float ds = dis[orow + r];
      __half* Hp = &H2[(size_t)(orow + r) * 64 + lr];
#pragma unroll
      for (int nt = 0; nt < 4; ++nt)
        Hp[nt * 16] = __float2half(acc[nt][r] * ds);
    }
  }
}

// pull-gather layer2: 16 lanes x uint2 per node, 16 nodes/block, unroll x4
__global__ __launch_bounds__(256) void k_gather2(const int* __restrict__ offS,
                                                 const int* __restrict__ offE,
                                                 const unsigned* __restrict__ sedge,
                                                 const float* __restrict__ dis,
                                                 const __half* __restrict__ H,
                                                 const float* __restrict__ b2,
                                                 float* __restrict__ O) {
  int node = blockIdx.x * 16 + (threadIdx.x >> 4);
  int f4 = threadIdx.x & 15;
  const uint2* Hh = (const uint2*)H;
  float4 acc = make_float4(0.f, 0.f, 0.f, 0.f);
  float dc = dis[node];
  int j0 = offS[node], j1 = offE[node];
  int j = j0;
  for (; j + 3 < j1; j += 4) {
    unsigned u0 = sedge[j], u1 = sedge[j + 1];
    unsigned u2 = sedge[j + 2], u3 = sedge[j + 3];
    uint2 r0 = Hh[(size_t)(u0 >> 16) * 16 + f4];
    uint2 r1 = Hh[(size_t)(u1 >> 16) * 16 + f4];
    uint2 r2 = Hh[(size_t)(u2 >> 16) * 16 + f4];
    uint2 r3 = Hh[(size_t)(u3 >> 16) * 16 + f4];
    float n0 = __half2float(__ushort_as_half((unsigned short)(u0 & 0xFFFFu)));
    float n1 = __half2float(__ushort_as_half((unsigned short)(u1 & 0xFFFFu)));
    float n2 = __half2float(__ushort_as_half((unsigned short)(u2 & 0xFFFFu)));
    float n3 = __half2float(__ushort_as_half((unsigned short)(u3 & 0xFFFFu)));
    float2 a0 = __half22float2(*(__half2*)&r0.x);
    float2 c0 = __half22float2(*(__half2*)&r0.y);
    float2 a1 = __half22float2(*(__half2*)&r1.x);
    float2 c1 = __half22float2(*(__half2*)&r1.y);
    float2 a2 = __half22float2(*(__half2*)&r2.x);
    float2 c2 = __half22float2(*(__half2*)&r2.y);
    float2 a3 = __half22float2(*(__half2*)&r3.x);
    float2 c3 = __half22float2(*(__half2*)&r3.y);
    acc.x = fmaf(a0.x, n0, acc.x); acc.y = fmaf(a0.y, n0, acc.y);
    acc.z = fmaf(c0.x, n0, acc.z); acc.w = fmaf(c0.y, n0, acc.w);
    acc.x = fmaf(a1.x, n1, acc.x); acc.y = fmaf(a1.y, n1, acc.y);
    acc.z = fmaf(c1.x, n1, acc.z); acc.w = fmaf(c1.y, n1, acc.w);
    acc.x = fmaf(a2.x, n2, acc.x); acc.y = fmaf(a2.y, n2, acc.y);
    acc.z = fmaf(c2.x, n2, acc.z); acc.w = fmaf(c2.y, n2, acc.w);
    acc.x = fmaf(a3.x, n3, acc.x); acc.y = fmaf(a3.y, n3, acc.y);
    acc.z = fmaf(c3.x, n3, acc.z); acc.w = fmaf(c3.y, n3, acc.w);
  }
  for (; j < j1; ++j) {
    unsigned u = sedge[j];
    uint2 r = Hh[(size_t)(u >> 16) * 16 + f4];
    float nm = __half2float(__ushort_as_half((unsigned short)(u & 0xFFFFu)));
    float2 a = __half22float2(*(__half2*)&r.x);
    float2 b = __half22float2(*(__half2*)&r.y);
    acc.x = fmaf(a.x, nm, acc.x); acc.y = fmaf(a.y, nm, acc.y);
    acc.z = fmaf(b.x, nm, acc.z); acc.w = fmaf(b.y, nm, acc.w);
  }
  float4 bl = ((const float4*)b2)[f4];
  float4 o;
  o.x = fmaf(acc.x, dc, bl.x);
  o.y = fmaf(acc.y, dc, bl.y);
  o.z = fmaf(acc.z, dc, bl.z);
  o.w = fmaf(acc.w, dc, bl.w);
  ((float4*)O)[(size_t)node * 16 + f4] = o;
}

__global__ void k_final(float* __restrict__ O, const float* __restrict__ sum2,
                        const float* __restrict__ sq2, const float* __restrict__ g2,
                        const float* __restrict__ be2) {
  int i = blockIdx.x * 256 + threadIdx.x;
  if (i < NN * 64) {
    int f = i & 63;
    float mu = sum2[f] * (1.0f / NN);
    float var = sq2[f] * (1.0f / NN) - mu * mu;
    float a = g2[f] * rsqrtf(var + EPSB);
    float c = be2[f] - mu * a;
    O[i] = fmaf(a, O[i], c);
  }
}

extern "C" void kernel_launch(void* const* d_in, const int* in_sizes, int n_in,
                              void* d_out, int out_size, void* d_ws, size_t ws_size,
                              hipStream_t stream) {
  const int* adj = (const int*)d_in[0];
  const float* w = (const float*)d_in[1];
  const float* X = (const float*)d_in[2];
  const float* W1 = (const float*)d_in[3];
  const float* b1 = (const float*)d_in[4];
  const float* g1 = (const float*)d_in[5];
  const float* be1 = (const float*)d_in[6];
  const float* W2 = (const float*)d_in[7];
  const float* b2 = (const float*)d_in[8];
  const float* g2 = (const float*)d_in[9];
  const float* be2 = (const float*)d_in[10];
  float* ws = (float*)d_ws;
  float* out = (float*)d_out;

  unsigned* sedge = (unsigned*)(ws + W_SEDGE);
  int* offS = (int*)(ws + W_OFFS);
  int* offE = (int*)(ws + W_OFFE);
  float* dis = ws + W_DIS;
  int* cnt_g = (int*)(ws + W_CNTG);
  float* sum1 = ws + W_SUM1;
  float* sq1 = ws + W_SQ1;
  float* sum2 = ws + W_SUM2;
  float* sq2 = ws + W_SQ2;
  int2* temp = (int2*)(ws + W_TEMP);
  __half* H1h = (__half*)(ws + W_H1);
  __half* H2h = (__half*)(ws + W_H1);  // aliases H1 (dead after gather1)
  __half* O1h = (__half*)(ws + W_O1);

  // zero bucket cursors + BN stats (one contiguous range)
  hipMemsetAsync(cnt_g, 0, (size_t)(W_SQ2 + 64 - W_CNTG) * sizeof(float), stream);

  k_scatC2<<<CB, 256, 0, stream>>>(adj, w, cnt_g, temp);
  k_binD2<<<NBKT, 256, 0, stream>>>(temp, cnt_g, dis, offS, offE, sedge);

  k_gemm1m<<<(NN + 63) / 64, 256, 0, stream>>>(X, W1, dis, H1h);
  k_gather1<<<NN / 8, 256, 0, stream>>>(offS, offE, sedge, dis, H1h, b1, O1h);
  k_statsh<<<512, 256, 0, stream>>>(O1h, sum1, sq1);

  k_gemm2m<<<(NN + 63) / 64, 256, 0, stream>>>(O1h, W2, sum1, sq1, g1, be1, dis, H2h);
  k_gather2<<<NN / 16, 256, 0, stream>>>(offS, offE, sedge, dis, H2h, b2, out);
  k_stats<<<512, 256, 0, stream>>>(out, sum2, sq2, 64);
  k_final<<<NN * 64 / 256, 256, 0, stream>>>(out, sum2, sq2, g2, be2);
}

// Round 14
// 274.306 us; speedup vs baseline: 1.0419x; 1.0419x over previous
//
#include <hip/hip_runtime.h>
#include <hip/hip_fp16.h>

#define NN 50000
#define NE 800000
#define NBKT 782          // ceil(NN/64) coarse buckets of 64 dests
#define CB 256            // scatter blocks (R14: 128->256, fill all CUs)
#define ECAP 1280         // fixed temp capacity per bucket (mean 1024, +8 sigma)
#define SCAP 1344         // sedge capacity per bucket (ECAP + 64 self slots)
#define EPSB 1e-5f
#define SLOPE 0.01f

// workspace layout (4-byte element offsets)
#define W_SEDGE 0          // NBKT*SCAP u32 = 1,051,008
#define W_OFFS  1051008    // NN ints
#define W_OFFE  1101008    // NN ints
#define W_DIS   1151008    // NN floats
#define W_CNTG  1201008    // NBKT ints (zeroed)
#define W_SUM1  1201792    // 128 (zeroed)
#define W_SQ1   1201920    // 128
#define W_SUM2  1202048    // 64
#define W_SQ2   1202112    // 64
#define W_TEMP  1202176    // NBKT*ECAP int2 = 2,001,920 ints (8B aligned: even)
#define W_H1    3204096    // N*128 fp16 = 3.2M float slots (H2 aliases)
#define W_O1    6404096    // N*128 fp16 = 3.2M float slots

union H8 { uint4 u; __half2 h[4]; };
typedef _Float16 f16x8 __attribute__((ext_vector_type(8)));
typedef float f32x4 __attribute__((ext_vector_type(4)));

// scatter with self-reserved bucket ranges
__global__ __launch_bounds__(256) void k_scatC2(const int* __restrict__ adj,
                                                const float* __restrict__ w,
                                                int* __restrict__ cnt_g,
                                                int2* __restrict__ temp) {
  __shared__ int h[NBKT];
  __shared__ int cur[NBKT];
  for (int i = threadIdx.x; i < NBKT; i += 256) h[i] = 0;
  __syncthreads();
  const int per = (NE + CB - 1) / CB;
  int lo = blockIdx.x * per, hi = min(lo + per, NE);
  for (int e = lo + threadIdx.x; e < hi; e += 256)
    atomicAdd(&h[adj[NE + e] >> 6], 1);
  __syncthreads();
  for (int i = threadIdx.x; i < NBKT; i += 256) {
    int c = h[i];
    int base = c ? atomicAdd(&cnt_g[i], c) : 0;
    cur[i] = i * ECAP + base;
  }
  __syncthreads();
  for (int e = lo + threadIdx.x; e < hi; e += 256) {
    int r = adj[e], c = adj[NE + e];
    int b = c >> 6;
    int slot = atomicAdd(&cur[b], 1);
    if (slot < (b + 1) * ECAP)
      temp[slot] = make_int2((r << 6) | (c & 63), __float_as_int(w[e]));
  }
}

// per-bucket binning (unchanged from R11)
__global__ __launch_bounds__(256) void k_binD2(const int2* __restrict__ temp,
                                               const int* __restrict__ cnt_g,
                                               float* __restrict__ dis,
                                               int* __restrict__ offS,
                                               int* __restrict__ offE,
                                               unsigned* __restrict__ sedge) {
  int k = blockIdx.x;
  int Tk = min(cnt_g[k], ECAP);
  int d0 = k << 6;
  int nd = min(64, NN - d0);
  int fbase = k * SCAP;
  const int2* tb = temp + (size_t)k * ECAP;
  __shared__ int cnt[64];
  __shared__ float wsum[64];
  __shared__ int lpos[64];
  __shared__ unsigned ob[SCAP];
  if (threadIdx.x < 64) { cnt[threadIdx.x] = 0; wsum[threadIdx.x] = 0.f; }
  __syncthreads();
  for (int i = threadIdx.x; i < Tk; i += 256) {
    int2 e = tb[i];
    int dl = e.x & 63;
    atomicAdd(&cnt[dl], 1);
    atomicAdd(&wsum[dl], __int_as_float(e.y));
  }
  __syncthreads();
  if (threadIdx.x < 64) {
    int lane = threadIdx.x;
    int c = (lane < nd) ? cnt[lane] + 1 : 0;
    int v = c;
#pragma unroll
    for (int o = 1; o < 64; o <<= 1) {
      int u = __shfl_up(v, o, 64);
      if (lane >= o) v += u;
    }
    int base = v - c;
    if (lane < nd) {
      dis[d0 + lane] = rsqrtf(wsum[lane] + 1.0f);
      offS[d0 + lane] = fbase + base;
      offE[d0 + lane] = fbase + base + c;
      ob[base] = ((unsigned)(d0 + lane) << 16) | 0x3C00u;  // self: fp16(1.0)
      lpos[lane] = base + 1;
    }
  }
  __syncthreads();
  for (int i = threadIdx.x; i < Tk; i += 256) {
    int2 e = tb[i];
    int dl = e.x & 63;
    unsigned src = ((unsigned)e.x) >> 6;
    int slot = atomicAdd(&lpos[dl], 1);
    __half hw = __float2half(__int_as_float(e.y));
    ob[slot] = (src << 16) | (unsigned)__half_as_ushort(hw);
  }
  __syncthreads();
  int tot = Tk + nd;
  for (int i = threadIdx.x; i < tot; i += 256)
    sedge[fbase + i] = ob[i];
}

// ---------------- MFMA GEMM1: H1(fp16) = X @ W1 ----------------
__global__ __launch_bounds__(256) void k_gemm1m(const float* __restrict__ X,
                                                const float* __restrict__ W1,
                                                __half* __restrict__ H) {
  __shared__ _Float16 xs[64 * 128];
  __shared__ _Float16 wt[128 * 128];
  char* xsb = (char*)xs;
  char* wtb = (char*)wt;
  int tid = threadIdx.x;
  int row0 = blockIdx.x * 64;
  for (int i = tid; i < 64 * 32; i += 256) {
    int r = i >> 5, c4 = i & 31;
    float4 v = (row0 + r < NN) ? ((const float4*)X)[(size_t)(row0 + r) * 32 + c4]
                               : make_float4(0.f, 0.f, 0.f, 0.f);
    union { _Float16 h[4]; uint2 u; } p;
    p.h[0] = (_Float16)v.x; p.h[1] = (_Float16)v.y;
    p.h[2] = (_Float16)v.z; p.h[3] = (_Float16)v.w;
    int byte = (r * 256 + c4 * 8) ^ ((r & 7) << 4);
    *(uint2*)(xsb + byte) = p.u;
  }
  for (int i = tid; i < 128 * 32; i += 256) {
    int k = i >> 5, n4 = i & 31;
    float4 v = ((const float4*)W1)[k * 32 + n4];
    float vv[4] = {v.x, v.y, v.z, v.w};
#pragma unroll
    for (int j = 0; j < 4; ++j) {
      int n = n4 * 4 + j;
      int byte = (n * 256 + k * 2) ^ ((n & 7) << 4);
      *(_Float16*)(wtb + byte) = (_Float16)vv[j];
    }
  }
  __syncthreads();
  int l = tid & 63, w = tid >> 6;
  int lr = l & 15, lk2 = ((l >> 4) << 3) * 2;
  f32x4 acc[8];
#pragma unroll
  for (int nt = 0; nt < 8; ++nt) acc[nt] = (f32x4){0.f, 0.f, 0.f, 0.f};
  int arow = w * 16 + lr;
  int asw = (arow & 7) << 4;
  int nsw = (lr & 7) << 4;
#pragma unroll
  for (int ks = 0; ks < 4; ++ks) {
    int kb = ks * 64 + lk2;
    f16x8 a = *(const f16x8*)(xsb + arow * 256 + (kb ^ asw));
#pragma unroll
    for (int nt = 0; nt < 8; ++nt) {
      int n = nt * 16 + lr;
      f16x8 b = *(const f16x8*)(wtb + n * 256 + (kb ^ nsw));
      acc[nt] = __builtin_amdgcn_mfma_f32_16x16x32_f16(a, b, acc[nt], 0, 0, 0);
    }
  }
  int orow = row0 + w * 16 + ((l >> 4) << 2);
#pragma unroll
  for (int r = 0; r < 4; ++r) {
    if (orow + r < NN) {
      __half* Hp = &H[(size_t)(orow + r) * 128 + lr];
#pragma unroll
      for (int nt = 0; nt < 8; ++nt)
        Hp[nt * 16] = __float2half(acc[nt][r]);
    }
  }
}

// pull-gather layer1: O(fp16)[c,:] = b1 + sum dis[s]*w*dis[c] * H[s,:]
// 32 lanes x uint2 per node, 8 nodes per 256-block, unroll x8 (R14)
__global__ __launch_bounds__(256) void k_gather1(const int* __restrict__ offS,
                                                 const int* __restrict__ offE,
                                                 const unsigned* __restrict__ sedge,
                                                 const float* __restrict__ dis,
                                                 const __half* __restrict__ H,
                                                 const float* __restrict__ b1,
                                                 __half* __restrict__ O) {
  int node = blockIdx.x * 8 + (threadIdx.x >> 5);
  int f4 = threadIdx.x & 31;
  const uint2* Hh = (const uint2*)H;
  float4 acc = ((const float4*)b1)[f4];
  float dc = dis[node];
  int j0 = offS[node], j1 = offE[node];
  int j = j0;
  for (; j + 7 < j1; j += 8) {
    unsigned u[8];
    uint2 r[8];
    float n[8];
#pragma unroll
    for (int q = 0; q < 8; ++q) u[q] = sedge[j + q];
#pragma unroll
    for (int q = 0; q < 8; ++q) r[q] = Hh[(size_t)(u[q] >> 16) * 32 + f4];
#pragma unroll
    for (int q = 0; q < 8; ++q)
      n[q] = dis[u[q] >> 16] *
             __half2float(__ushort_as_half((unsigned short)(u[q] & 0xFFFFu))) * dc;
#pragma unroll
    for (int q = 0; q < 8; ++q) {
      float2 a = __half22float2(*(__half2*)&r[q].x);
      float2 b = __half22float2(*(__half2*)&r[q].y);
      acc.x = fmaf(a.x, n[q], acc.x);
      acc.y = fmaf(a.y, n[q], acc.y);
      acc.z = fmaf(b.x, n[q], acc.z);
      acc.w = fmaf(b.y, n[q], acc.w);
    }
  }
  for (; j < j1; ++j) {
    unsigned u = sedge[j];
    unsigned s = u >> 16;
    uint2 r = Hh[(size_t)s * 32 + f4];
    float nm = dis[s] * __half2float(__ushort_as_half((unsigned short)(u & 0xFFFFu))) * dc;
    float2 a = __half22float2(*(__half2*)&r.x);
    float2 b = __half22float2(*(__half2*)&r.y);
    acc.x = fmaf(a.x, nm, acc.x);
    acc.y = fmaf(a.y, nm, acc.y);
    acc.z = fmaf(b.x, nm, acc.z);
    acc.w = fmaf(b.y, nm, acc.w);
  }
  uint2 o;
  *(__half2*)&o.x = __floats2half2_rn(acc.x, acc.y);
  *(__half2*)&o.y = __floats2half2_rn(acc.z, acc.w);
  ((uint2*)O)[(size_t)node * 32 + f4] = o;
}

__global__ __launch_bounds__(256) void k_statsh(const __half* __restrict__ X,
                                                float* __restrict__ sum,
                                                float* __restrict__ sq) {
  int f2 = threadIdx.x & 63;
  int rg = threadIdx.x >> 6;
  float sx = 0.f, sy = 0.f, ssx = 0.f, ssy = 0.f;
  const unsigned* X2 = (const unsigned*)X;
  for (int r = blockIdx.x * 4 + rg; r < NN; r += gridDim.x * 4) {
    unsigned u = X2[(size_t)r * 64 + f2];
    float2 v = __half22float2(*(__half2*)&u);
    sx += v.x; sy += v.y;
    ssx += v.x * v.x; ssy += v.y * v.y;
  }
  __shared__ float ls[256][4];
  ls[threadIdx.x][0] = sx; ls[threadIdx.x][1] = sy;
  ls[threadIdx.x][2] = ssx; ls[threadIdx.x][3] = ssy;
  __syncthreads();
  if (rg == 0) {
    for (int g = 1; g < 4; ++g) {
      sx += ls[g * 64 + f2][0]; sy += ls[g * 64 + f2][1];
      ssx += ls[g * 64 + f2][2]; ssy += ls[g * 64 + f2][3];
    }
    atomicAdd(&sum[2 * f2], sx);
    atomicAdd(&sum[2 * f2 + 1], sy);
    atomicAdd(&sq[2 * f2], ssx);
    atomicAdd(&sq[2 * f2 + 1], ssy);
  }
}

__global__ void k_stats(const float* __restrict__ X, float* __restrict__ sum,
                        float* __restrict__ sq, int C) {
  int f = threadIdx.x & (C - 1);
  int rg = threadIdx.x / C;
  int nrg = 256 / C;
  float s = 0.f, ss = 0.f;
  for (int r = blockIdx.x * nrg + rg; r < NN; r += gridDim.x * nrg) {
    float v = X[(size_t)r * C + f];
    s += v;
    ss += v * v;
  }
  __shared__ float ls[256], lss[256];
  ls[threadIdx.x] = s;
  lss[threadIdx.x] = ss;
  __syncthreads();
  if (rg == 0) {
    for (int g = 1; g < nrg; ++g) { s += ls[g * C + f]; ss += lss[g * C + f]; }
    atomicAdd(&sum[f], s);
    atomicAdd(&sq[f], ss);
  }
}

// ---------------- MFMA GEMM2: H2(fp16) = leaky(BN1(O1)) @ W2 ----------------
__global__ __launch_bounds__(256) void k_gemm2m(const __half* __restrict__ O1,
                                                const float* __restrict__ W2,
                                                const float* __restrict__ sum1,
                                                const float* __restrict__ sq1,
                                                const float* __restrict__ g1,
                                                const float* __restrict__ be1,
                                                __half* __restrict__ H2) {
  __shared__ _Float16 xs[64 * 128];
  __shared__ _Float16 wt[64 * 128];
  __shared__ float a1s[128], c1s[128];
  char* xsb = (char*)xs;
  char* wtb = (char*)wt;
  int tid = threadIdx.x;
  if (tid < 128) {
    float mu = sum1[tid] * (1.0f / NN);
    float var = sq1[tid] * (1.0f / NN) - mu * mu;
    float a = g1[tid] * rsqrtf(var + EPSB);
    a1s[tid] = a;
    c1s[tid] = be1[tid] - mu * a;
  }
  __syncthreads();
  int row0 = blockIdx.x * 64;
  for (int i = tid; i < 64 * 16; i += 256) {
    int r = i >> 4, k8 = i & 15;
    H8 t;
    t.u = (row0 + r < NN) ? ((const uint4*)O1)[(size_t)(row0 + r) * 16 + k8]
                          : make_uint4(0, 0, 0, 0);
    union { _Float16 h[8]; uint4 u; } p;
#pragma unroll
    for (int jj = 0; jj < 4; ++jj) {
      float2 v = __half22float2(t.h[jj]);
      int fb = k8 * 8 + jj * 2;
      float y0 = fmaf(a1s[fb], v.x, c1s[fb]);
      float y1 = fmaf(a1s[fb + 1], v.y, c1s[fb + 1]);
      y0 = y0 >= 0.f ? y0 : SLOPE * y0;
      y1 = y1 >= 0.f ? y1 : SLOPE * y1;
      p.h[jj * 2] = (_Float16)y0;
      p.h[jj * 2 + 1] = (_Float16)y1;
    }
    int byte = (r * 256 + k8 * 16) ^ ((r & 7) << 4);
    *(uint4*)(xsb + byte) = p.u;
  }
  for (int i = tid; i < 128 * 16; i += 256) {
    int k = i >> 4, n4 = i & 15;
    float4 v = ((const float4*)W2)[k * 16 + n4];
    float vv[4] = {v.x, v.y, v.z, v.w};
#pragma unroll
    for (int j = 0; j < 4; ++j) {
      int n = n4 * 4 + j;
      int byte = (n * 256 + k * 2) ^ ((n & 7) << 4);
      *(_Float16*)(wtb + byte) = (_Float16)vv[j];
    }
  }
  __syncthreads();
  int l = tid & 63, w = tid >> 6;
  int lr = l & 15, lk2 = ((l >> 4) << 3) * 2;
  f32x4 acc[4];
#pragma unroll
  for (int nt = 0; nt < 4; ++nt) acc[nt] = (f32x4){0.f, 0.f, 0.f, 0.f};
  int arow = w * 16 + lr;
  int asw = (arow & 7) << 4;
  int nsw = (lr & 7) << 4;
#pragma unroll
  for (int ks = 0; ks < 4; ++ks) {
    int kb = ks * 64 + lk2;
    f16x8 a = *(const f16x8*)(xsb + arow * 256 + (kb ^ asw));
#pragma unroll
    for (int nt = 0; nt < 4; ++nt) {
      int n = nt * 16 + lr;
      f16x8 b = *(const f16x8*)(wtb + n * 256 + (kb ^ nsw));
      acc[nt] = __builtin_amdgcn_mfma_f32_16x16x32_f16(a, b, acc[nt], 0, 0, 0);
    }
  }
  int orow = row0 + w * 16 + ((l >> 4) << 2);
#pragma unroll
  for (int r = 0; r < 4; ++r) {
    if (orow + r < NN) {
      __half* Hp = &H2[(size_t)(orow + r) * 64 + lr];
#pragma unroll
      for (int nt = 0; nt < 4; ++nt)
        Hp[nt * 16] = __float2half(acc[nt][r]);
    }
  }
}

// pull-gather layer2: 16 lanes x uint2 per node, 16 nodes/block, unroll x4
__global__ __launch_bounds__(256) void k_gather2(const int* __restrict__ offS,
                                                 const int* __restrict__ offE,
                                                 const unsigned* __restrict__ sedge,
                                                 const float* __restrict__ dis,
                                                 const __half* __restrict__ H,
                                                 const float* __restrict__ b2,
                                                 float* __restrict__ O) {
  int node = blockIdx.x * 16 + (threadIdx.x >> 4);
  int f4 = threadIdx.x & 15;
  const uint2* Hh = (const uint2*)H;
  float4 acc = ((const float4*)b2)[f4];
  float dc = dis[node];
  int j0 = offS[node], j1 = offE[node];
  int j = j0;
  for (; j + 3 < j1; j += 4) {
    unsigned u0 = sedge[j], u1 = sedge[j + 1];
    unsigned u2 = sedge[j + 2], u3 = sedge[j + 3];
    unsigned s0 = u0 >> 16, s1 = u1 >> 16, s2 = u2 >> 16, s3 = u3 >> 16;
    uint2 r0 = Hh[(size_t)s0 * 16 + f4];
    uint2 r1 = Hh[(size_t)s1 * 16 + f4];
    uint2 r2 = Hh[(size_t)s2 * 16 + f4];
    uint2 r3 = Hh[(size_t)s3 * 16 + f4];
    float n0 = dis[s0] * __half2float(__ushort_as_half((unsigned short)(u0 & 0xFFFFu))) * dc;
    float n1 = dis[s1] * __half2float(__ushort_as_half((unsigned short)(u1 & 0xFFFFu))) * dc;
    float n2 = dis[s2] * __half2float(__ushort_as_half((unsigned short)(u2 & 0xFFFFu))) * dc;
    float n3 = dis[s3] * __half2float(__ushort_as_half((unsigned short)(u3 & 0xFFFFu))) * dc;
    float2 a0 = __half22float2(*(__half2*)&r0.x);
    float2 c0 = __half22float2(*(__half2*)&r0.y);
    float2 a1 = __half22float2(*(__half2*)&r1.x);
    float2 c1 = __half22float2(*(__half2*)&r1.y);
    float2 a2 = __half22float2(*(__half2*)&r2.x);
    float2 c2 = __half22float2(*(__half2*)&r2.y);
    float2 a3 = __half22float2(*(__half2*)&r3.x);
    float2 c3 = __half22float2(*(__half2*)&r3.y);
    acc.x = fmaf(a0.x, n0, acc.x); acc.y = fmaf(a0.y, n0, acc.y);
    acc.z = fmaf(c0.x, n0, acc.z); acc.w = fmaf(c0.y, n0, acc.w);
    acc.x = fmaf(a1.x, n1, acc.x); acc.y = fmaf(a1.y, n1, acc.y);
    acc.z = fmaf(c1.x, n1, acc.z); acc.w = fmaf(c1.y, n1, acc.w);
    acc.x = fmaf(a2.x, n2, acc.x); acc.y = fmaf(a2.y, n2, acc.y);
    acc.z = fmaf(c2.x, n2, acc.z); acc.w = fmaf(c2.y, n2, acc.w);
    acc.x = fmaf(a3.x, n3, acc.x); acc.y = fmaf(a3.y, n3, acc.y);
    acc.z = fmaf(c3.x, n3, acc.z); acc.w = fmaf(c3.y, n3, acc.w);
  }
  for (; j < j1; ++j) {
    unsigned u = sedge[j];
    unsigned s = u >> 16;
    uint2 r = Hh[(size_t)s * 16 + f4];
    float nm = dis[s] * __half2float(__ushort_as_half((unsigned short)(u & 0xFFFFu))) * dc;
    float2 a = __half22float2(*(__half2*)&r.x);
    float2 b = __half22float2(*(__half2*)&r.y);
    acc.x = fmaf(a.x, nm, acc.x); acc.y = fmaf(a.y, nm, acc.y);
    acc.z = fmaf(b.x, nm, acc.z); acc.w = fmaf(b.y, nm, acc.w);
  }
  ((float4*)O)[(size_t)node * 16 + f4] = acc;
}

__global__ void k_final(float* __restrict__ O, const float* __restrict__ sum2,
                        const float* __restrict__ sq2, const float* __restrict__ g2,
                        const float* __restrict__ be2) {
  int i = blockIdx.x * 256 + threadIdx.x;
  if (i < NN * 64) {
    int f = i & 63;
    float mu = sum2[f] * (1.0f / NN);
    float var = sq2[f] * (1.0f / NN) - mu * mu;
    float a = g2[f] * rsqrtf(var + EPSB);
    float c = be2[f] - mu * a;
    O[i] = fmaf(a, O[i], c);
  }
}

extern "C" void kernel_launch(void* const* d_in, const int* in_sizes, int n_in,
                              void* d_out, int out_size, void* d_ws, size_t ws_size,
                              hipStream_t stream) {
  const int* adj = (const int*)d_in[0];
  const float* w = (const float*)d_in[1];
  const float* X = (const float*)d_in[2];
  const float* W1 = (const float*)d_in[3];
  const float* b1 = (const float*)d_in[4];
  const float* g1 = (const float*)d_in[5];
  const float* be1 = (const float*)d_in[6];
  const float* W2 = (const float*)d_in[7];
  const float* b2 = (const float*)d_in[8];
  const float* g2 = (const float*)d_in[9];
  const float* be2 = (const float*)d_in[10];
  float* ws = (float*)d_ws;
  float* out = (float*)d_out;

  unsigned* sedge = (unsigned*)(ws + W_SEDGE);
  int* offS = (int*)(ws + W_OFFS);
  int* offE = (int*)(ws + W_OFFE);
  float* dis = ws + W_DIS;
  int* cnt_g = (int*)(ws + W_CNTG);
  float* sum1 = ws + W_SUM1;
  float* sq1 = ws + W_SQ1;
  float* sum2 = ws + W_SUM2;
  float* sq2 = ws + W_SQ2;
  int2* temp = (int2*)(ws + W_TEMP);
  __half* H1h = (__half*)(ws + W_H1);
  __half* H2h = (__half*)(ws + W_H1);  // aliases H1 (dead after gather1)
  __half* O1h = (__half*)(ws + W_O1);

  // zero bucket cursors + BN stats (one contiguous range)
  hipMemsetAsync(cnt_g, 0, (size_t)(W_SQ2 + 64 - W_CNTG) * sizeof(float), stream);

  k_scatC2<<<CB, 256, 0, stream>>>(adj, w, cnt_g, temp);
  k_binD2<<<NBKT, 256, 0, stream>>>(temp, cnt_g, dis, offS, offE, sedge);

  k_gemm1m<<<(NN + 63) / 64, 256, 0, stream>>>(X, W1, H1h);
  k_gather1<<<NN / 8, 256, 0, stream>>>(offS, offE, sedge, dis, H1h, b1, O1h);
  k_statsh<<<512, 256, 0, stream>>>(O1h, sum1, sq1);

  k_gemm2m<<<(NN + 63) / 64, 256, 0, stream>>>(O1h, W2, sum1, sq1, g1, be1, H2h);
  k_gather2<<<NN / 16, 256, 0, stream>>>(offS, offE, sedge, dis, H2h, b2, out);
  k_stats<<<512, 256, 0, stream>>>(out, sum2, sq2, 64);
  k_final<<<NN * 64 / 256, 256, 0, stream>>>(out, sum2, sq2, g2, be2);
}